// Round 7
// baseline (1761.457 us; speedup 1.0000x reference)
//
#include <hip/hip_runtime.h>
#include <math.h>

#define WAYS 32
#define NTOT 2048
#define XD 84
#define FLAT 3610
#define KSPLIT 16
#define KCHUNK 226  // ceil(3610/16)

__device__ __forceinline__ float softplus_f(float x) {
    return (x > 20.f) ? x : log1pf(expf(x));
}
__device__ __forceinline__ float kl_f(float mu, float sd) {
    return -logf(sd) + 0.5f * (sd * sd + mu * mu) - 0.5f;
}

// ---------------------------------------------------------------------------
// Fused conv1+relu+pool -> conv2+relu+pool.
// Grid: 2048 images x 5 bands of p2 rows (4,4,4,4,3).
// Conservative codegen: scalar LDS accesses only (no vector casts, no
// cross-lane builtins). Weights staged to LDS in native layout; inner-loop
// weight reads are wave-broadcast (conflict-free). Register-tiled 2x2 pool
// window shares taps across the window: conv1 = 48 x-reads + 270 w-reads
// per 1080 FMA; conv2 = 160 + 450 per 900 FMA.
// ---------------------------------------------------------------------------
__global__ __launch_bounds__(256, 2) void k_conv(
        const float* __restrict__ x,
        const float* __restrict__ w1, const float* __restrict__ b1,
        const float* __restrict__ w2, const float* __restrict__ b2,
        float* __restrict__ p2) {
    __shared__ float xs[3 * 22 * 84];      // [c][row][col]  22176 B
    __shared__ float p1s[10 * 10 * 40];    // [ic][q][col]   16000 B
    __shared__ float w1s[270];             // native layout [oc][c][3][3]
    __shared__ float w2s[900];             // native layout [oc][ic][3][3]

    const int tid  = threadIdx.x;
    const int img  = blockIdx.x & 2047;
    const int band = blockIdx.x >> 11;       // 0..4
    const int r0   = band * 4;               // first p2 row
    const int nr   = (band < 4) ? 4 : 3;     // p2 rows in band
    const int nq   = 2 * nr + 2;             // p1 rows needed (10 or 8)
    const int xr0  = 16 * band;              // first x row (0,16,32,48,64)
    const int nxr  = 2 * nq + 2;             // x rows (22 or 18)

    // ---- stage x band (coalesced scalar copies) ----
    {
        const float* xg = x + (size_t)img * (3 * XD * XD);
        const int per_c = nxr * 84;          // 1848 or 1512
        #pragma unroll
        for (int c = 0; c < 3; c++) {
            const float* src = xg + c * (XD * XD) + xr0 * 84;
            float* dst = xs + c * (22 * 84);
            for (int i = tid; i < per_c; i += 256) dst[i] = src[i];
        }
    }
    // ---- stage weights (native layout, scalar copies) ----
    for (int i = tid; i < 270; i += 256) w1s[i] = w1[i];
    for (int i = tid; i < 900; i += 256) w2s[i] = w2[i];
    __syncthreads();

    // ---- conv1 + relu + pool -> p1s ----
    {
        const int n1 = nq * 40;              // 400 or 320
        for (int it = tid; it < n1; it += 256) {
            int q = it / 40;                 // local p1 row
            int p = it - q * 40;             // p1 col
            float acc[10][4];
            #pragma unroll
            for (int o = 0; o < 10; o++)
                #pragma unroll
                for (int j = 0; j < 4; j++) acc[o][j] = 0.f;
            for (int c = 0; c < 3; c++) {
                float xp[4][4];
                #pragma unroll
                for (int rr = 0; rr < 4; rr++)
                    #pragma unroll
                    for (int cc = 0; cc < 4; cc++)
                        xp[rr][cc] = xs[c * (22 * 84) + (2 * q + rr) * 84 + (2 * p + cc)];
                #pragma unroll
                for (int ky = 0; ky < 3; ky++) {
                    #pragma unroll
                    for (int kx = 0; kx < 3; kx++) {
                        #pragma unroll
                        for (int o = 0; o < 10; o++) {
                            float w = w1s[(o * 3 + c) * 9 + ky * 3 + kx];
                            acc[o][0] = fmaf(xp[ky][kx],         w, acc[o][0]);
                            acc[o][1] = fmaf(xp[ky][kx + 1],     w, acc[o][1]);
                            acc[o][2] = fmaf(xp[ky + 1][kx],     w, acc[o][2]);
                            acc[o][3] = fmaf(xp[ky + 1][kx + 1], w, acc[o][3]);
                        }
                    }
                }
            }
            #pragma unroll
            for (int o = 0; o < 10; o++) {
                float m = fmaxf(fmaxf(acc[o][0], acc[o][1]), fmaxf(acc[o][2], acc[o][3]));
                p1s[o * 400 + q * 40 + p] = fmaxf(m + b1[o], 0.f);
            }
        }
    }
    __syncthreads();

    // ---- conv2 + relu + pool -> p2 (global) ----
    // 152 items: (pos 0..75) x (half 0..1); 5 output channels per item.
    {
        const int npos = nr * 19;            // 76 or 57
        if (tid < 152) {
            int half = (tid >= 76) ? 1 : 0;
            int pos  = tid - 76 * half;
            if (pos < npos) {
                int pr = pos / 19;           // local p2 row
                int pc = pos - pr * 19;
                float acc[5][4];
                #pragma unroll
                for (int o = 0; o < 5; o++)
                    #pragma unroll
                    for (int j = 0; j < 4; j++) acc[o][j] = 0.f;
                for (int ic = 0; ic < 10; ic++) {
                    float xp[4][4];
                    #pragma unroll
                    for (int rr = 0; rr < 4; rr++)
                        #pragma unroll
                        for (int cc = 0; cc < 4; cc++)
                            xp[rr][cc] = p1s[ic * 400 + (2 * pr + rr) * 40 + (2 * pc + cc)];
                    #pragma unroll
                    for (int ky = 0; ky < 3; ky++) {
                        #pragma unroll
                        for (int kx = 0; kx < 3; kx++) {
                            #pragma unroll
                            for (int o = 0; o < 5; o++) {
                                float w = w2s[((half * 5 + o) * 10 + ic) * 9 + ky * 3 + kx];
                                acc[o][0] = fmaf(xp[ky][kx],         w, acc[o][0]);
                                acc[o][1] = fmaf(xp[ky][kx + 1],     w, acc[o][1]);
                                acc[o][2] = fmaf(xp[ky + 1][kx],     w, acc[o][2]);
                                acc[o][3] = fmaf(xp[ky + 1][kx + 1], w, acc[o][3]);
                            }
                        }
                    }
                }
                float* outp = p2 + (size_t)img * FLAT;
                #pragma unroll
                for (int o = 0; o < 5; o++) {
                    int oc = half * 5 + o;
                    float m = fmaxf(fmaxf(acc[o][0], acc[o][1]), fmaxf(acc[o][2], acc[o][3]));
                    outp[oc * 361 + (r0 + pr) * 19 + pc] = fmaxf(m + b2[oc], 0.f);
                }
            }
        }
    }
}

// ---------------------------------------------------------------------------
__global__ void k_label(const float* __restrict__ y, int* __restrict__ label) {
    int n = blockIdx.x * 256 + threadIdx.x;
    if (n >= NTOT) return;
    const float* yr = y + n * WAYS;
    float best = yr[0]; int bi = 0;
    for (int k = 1; k < WAYS; k++) {
        float v = yr[k];
        if (v > best) { best = v; bi = k; }
    }
    label[n] = bi;
}

// ---------------------------------------------------------------------------
// enc GEMM: H[2048,64] += p2[2048,3610] @ enc_w[3610,64]  (split-K, atomics)
// ---------------------------------------------------------------------------
__global__ __launch_bounds__(256, 2) void k_enc(
        const float* __restrict__ A, const float* __restrict__ W,
        float* __restrict__ H) {
    __shared__ float a_s[32 * 66];
    __shared__ float w_s[32 * 64];
    int mb = blockIdx.x >> 4;
    int ks = blockIdx.x & 15;
    int row0 = mb * 64;
    int kbeg = ks * KCHUNK;
    int kend = min(kbeg + KCHUNK, FLAT);
    int tid = threadIdx.x;
    int tr = tid & 15, tc = tid >> 4;
    float acc[4][4] = {};

    for (int k0 = kbeg; k0 < kend; k0 += 32) {
        {
            int kk = tid & 31;
            int r  = tid >> 5;
            int gk = k0 + kk;
            #pragma unroll
            for (int i = 0; i < 8; i++) {
                int rr = r + i * 8;
                float v = (gk < kend) ? A[(size_t)(row0 + rr) * FLAT + gk] : 0.f;
                a_s[kk * 66 + rr] = v;
            }
            int c  = tid & 63;
            int kw = tid >> 6;
            #pragma unroll
            for (int i = 0; i < 8; i++) {
                int kk2 = kw + i * 4;
                int gk2 = k0 + kk2;
                float v = (gk2 < kend) ? W[(size_t)gk2 * 64 + c] : 0.f;
                w_s[kk2 * 64 + c] = v;
            }
        }
        __syncthreads();
        #pragma unroll 8
        for (int k = 0; k < 32; k++) {
            float av[4], wv[4];
            #pragma unroll
            for (int i = 0; i < 4; i++) av[i] = a_s[k * 66 + tr * 4 + i];
            #pragma unroll
            for (int j = 0; j < 4; j++) wv[j] = w_s[k * 64 + tc * 4 + j];
            #pragma unroll
            for (int i = 0; i < 4; i++)
                #pragma unroll
                for (int j = 0; j < 4; j++)
                    acc[i][j] = fmaf(av[i], wv[j], acc[i][j]);
        }
        __syncthreads();
    }
    #pragma unroll
    for (int i = 0; i < 4; i++)
        #pragma unroll
        for (int j = 0; j < 4; j++)
            atomicAdd(&H[(size_t)(row0 + tr * 4 + i) * 64 + tc * 4 + j], acc[i][j]);
}

// ---------------------------------------------------------------------------
__global__ __launch_bounds__(256) void k_stats(
        const float* __restrict__ H, const float* __restrict__ encb,
        const int* __restrict__ label,
        const float* __restrict__ t1w, const float* __restrict__ t1b,
        float* __restrict__ cs, float* __restrict__ card) {
    __shared__ float rs[4][64], rs2[4][64];
    __shared__ int rc[4];
    int w = blockIdx.x;
    int tid = threadIdx.x;
    int c = tid & 63, g = tid >> 6;
    float s = 0.f, s2 = 0.f; int cnt = 0;
    for (int n = g; n < NTOT; n += 4) {
        if (label[n] == w) {
            float hv = H[n * 64 + c] + encb[c];
            s += hv; s2 += hv * hv; cnt++;
        }
    }
    rs[g][c] = s; rs2[g][c] = s2;
    if (c == 0) rc[g] = cnt;
    __syncthreads();
    if (g == 0) {
        float S  = rs[0][c] + rs[1][c] + rs[2][c] + rs[3][c];
        float S2 = rs2[0][c] + rs2[1][c] + rs2[2][c] + rs2[3][c];
        int CNT  = rc[0] + rc[1] + rc[2] + rc[3];
        float mean = S / 2048.f;
        float var  = (S2 - S * S / 2048.f) / 2047.f;
        float cd   = ((float)CNT - 1.f) / 63.f;
        #pragma unroll
        for (int j = 0; j < 4; j++)
            cs[w * 256 + c * 4 + j] =
                fmaxf(mean * t1w[j] + var * t1w[4 + j] + cd * t1w[8 + j] + t1b[j], 0.f);
        if (c == 0) card[w] = cd;
    }
}

// ---------------------------------------------------------------------------
__global__ __launch_bounds__(256) void k_head(
        const float* __restrict__ cs_g, const float* __restrict__ card,
        const float* __restrict__ te2w1, const float* __restrict__ te2b1,
        const float* __restrict__ te2w2, const float* __restrict__ te2b2,
        const float* __restrict__ t2w, const float* __restrict__ t2b,
        const float* __restrict__ omw, const float* __restrict__ omb,
        const float* __restrict__ osw, const float* __restrict__ osb,
        const float* __restrict__ gaw, const float* __restrict__ gab,
        const float* __restrict__ gmw, const float* __restrict__ gmb,
        const float* __restrict__ gsw, const float* __restrict__ gsb,
        const float* __restrict__ zew, const float* __restrict__ zeb,
        const float* __restrict__ zmw, const float* __restrict__ zmb,
        const float* __restrict__ zsw, const float* __restrict__ zsb,
        float* __restrict__ out) {
    __shared__ float cst[256 * 36];
    __shared__ float a1t[128 * 36];
    __shared__ float ts[32 * 32];
    __shared__ float tv[128];
    __shared__ float eg_s[64], ez_s[64];
    __shared__ float red[256];
    int tid = threadIdx.x;

    for (int i = tid; i < 32 * 256; i += 256) {
        int w = i >> 8, k = i & 255;
        cst[k * 36 + w] = cs_g[i];
    }
    __syncthreads();

    {
        int wg = tid >> 5, jg = tid & 31;
        int w0 = wg * 4, j0 = jg * 4;
        float acc[4][4] = {};
        for (int k = 0; k < 256; k++) {
            float cva[4], wva[4];
            #pragma unroll
            for (int i = 0; i < 4; i++) cva[i] = cst[k * 36 + w0 + i];
            #pragma unroll
            for (int j = 0; j < 4; j++) wva[j] = te2w1[k * 128 + j0 + j];
            #pragma unroll
            for (int i = 0; i < 4; i++)
                #pragma unroll
                for (int j = 0; j < 4; j++)
                    acc[i][j] = fmaf(cva[i], wva[j], acc[i][j]);
        }
        #pragma unroll
        for (int jj = 0; jj < 4; jj++) {
            float b = te2b1[j0 + jj];
            #pragma unroll
            for (int i = 0; i < 4; i++)
                a1t[(j0 + jj) * 36 + w0 + i] = fmaxf(acc[i][jj] + b, 0.f);
        }
    }
    __syncthreads();

    {
        int wg = tid >> 4, jg = tid & 15;
        int w0 = wg * 2, j0 = jg * 2;
        float acc[2][2] = {};
        for (int k = 0; k < 128; k++) {
            float a0 = a1t[k * 36 + w0];
            float a1 = a1t[k * 36 + w0 + 1];
            float b0 = te2w2[k * 32 + j0];
            float b1v = te2w2[k * 32 + j0 + 1];
            acc[0][0] = fmaf(a0, b0, acc[0][0]);
            acc[0][1] = fmaf(a0, b1v, acc[0][1]);
            acc[1][0] = fmaf(a1, b0, acc[1][0]);
            acc[1][1] = fmaf(a1, b1v, acc[1][1]);
        }
        #pragma unroll
        for (int i = 0; i < 2; i++)
            #pragma unroll
            for (int j = 0; j < 2; j++)
                ts[(w0 + i) * 32 + (j0 + j)] = acc[i][j] + te2b2[j0 + j];
    }
    __syncthreads();

    float muo = 0.f, sdo = 1.f;
    if (tid < 32) {
        float csum = 0.f;
        for (int w2 = 0; w2 < 32; w2++) csum += card[w2];
        float s = 0.f, s2 = 0.f;
        for (int w2 = 0; w2 < 32; w2++) { float v = ts[w2 * 32 + tid]; s += v; s2 += v * v; }
        float m  = s / 32.f;
        float vv = (s2 - s * s / 32.f) / 31.f;
        #pragma unroll
        for (int j = 0; j < 4; j++)
            tv[tid * 4 + j] = fmaxf(m * t2w[j] + vv * t2w[4 + j] + csum * t2w[8 + j] + t2b[j], 0.f);
    } else if (tid < 64) {
        int w = tid - 32;
        float am = 0.f, as = 0.f;
        for (int k = 0; k < 256; k++) {
            float cv = cst[k * 36 + w];
            am = fmaf(cv, omw[k], am);
            as = fmaf(cv, osw[k], as);
        }
        muo = fmaxf(am + omb[0], 0.f);
        sdo = softplus_f(fmaxf(as + osb[0], 0.f));
        out[w] = muo;
    }
    __syncthreads();

    if (tid >= 64 && tid < 128) {
        int j = tid - 64;
        float ag = gab[j], az = zeb[j];
        for (int k = 0; k < 128; k++) {
            float t = tv[k];
            ag = fmaf(t, gaw[k * 64 + j], ag);
            az = fmaf(t, zew[k * 64 + j], az);
        }
        eg_s[j] = fmaxf(ag, 0.f);
        ez_s[j] = fmaxf(az, 0.f);
    }
    __syncthreads();

    float r = 0.f;
    {
        int j = tid;
        float am = zmb[j], as = zsb[j];
        for (int k = 0; k < 64; k++) {
            float e = ez_s[k];
            am = fmaf(e, zmw[k * 256 + j], am);
            as = fmaf(e, zsw[k * 256 + j], as);
        }
        float mu = fmaxf(am, 0.f);
        float sd = softplus_f(fmaxf(as, 0.f));
        out[37 + j] = mu;
        r += kl_f(mu, sd);
    }
    if (tid < 5) {
        float am = gmb[tid], as = gsb[tid];
        for (int k = 0; k < 64; k++) {
            float e = eg_s[k];
            am = fmaf(e, gmw[k * 5 + tid], am);
            as = fmaf(e, gsw[k * 5 + tid], as);
        }
        float mu = fmaxf(am, 0.f);
        float sd = softplus_f(fmaxf(as, 0.f));
        out[32 + tid] = mu;
        r += kl_f(mu, sd);
    }
    if (tid >= 32 && tid < 64) r += kl_f(muo, sdo);
    red[tid] = r;
    __syncthreads();
    for (int s = 128; s > 0; s >>= 1) {
        if (tid < s) red[tid] += red[tid + s];
        __syncthreads();
    }
    if (tid == 0) out[293] = red[0];
}

// ---------------------------------------------------------------------------
extern "C" void kernel_launch(void* const* d_in, const int* in_sizes, int n_in,
                              void* d_out, int out_size, void* d_ws, size_t ws_size,
                              hipStream_t stream) {
    const float* x    = (const float*)d_in[0];
    const float* y    = (const float*)d_in[1];
    const float* w1   = (const float*)d_in[2];
    const float* b1   = (const float*)d_in[3];
    const float* w2   = (const float*)d_in[4];
    const float* b2   = (const float*)d_in[5];
    const float* encw = (const float*)d_in[6];
    const float* encb = (const float*)d_in[7];
    const float* t1w  = (const float*)d_in[8];
    const float* t1b  = (const float*)d_in[9];
    const float* te2w1 = (const float*)d_in[10];
    const float* te2b1 = (const float*)d_in[11];
    const float* te2w2 = (const float*)d_in[12];
    const float* te2b2 = (const float*)d_in[13];
    const float* t2w  = (const float*)d_in[14];
    const float* t2b  = (const float*)d_in[15];
    const float* omw  = (const float*)d_in[16];
    const float* omb  = (const float*)d_in[17];
    const float* osw  = (const float*)d_in[18];
    const float* osb  = (const float*)d_in[19];
    const float* gaw  = (const float*)d_in[20];
    const float* gab  = (const float*)d_in[21];
    const float* gmw  = (const float*)d_in[22];
    const float* gmb  = (const float*)d_in[23];
    const float* gsw  = (const float*)d_in[24];
    const float* gsb  = (const float*)d_in[25];
    const float* zew  = (const float*)d_in[26];
    const float* zeb  = (const float*)d_in[27];
    const float* zmw  = (const float*)d_in[28];
    const float* zmb  = (const float*)d_in[29];
    const float* zsw  = (const float*)d_in[30];
    const float* zsb  = (const float*)d_in[31];
    float* out = (float*)d_out;

    float* p2   = (float*)d_ws;                       // [2048][3610]
    float* H    = p2 + (size_t)NTOT * FLAT;           // [2048][64]
    int*   lbl  = (int*)(H + NTOT * 64);              // [2048]
    float* cs   = (float*)(lbl + NTOT);               // [32][256]
    float* card = cs + 32 * 256;                      // [32]

    hipMemsetAsync(H, 0, NTOT * 64 * sizeof(float), stream);
    hipLaunchKernelGGL(k_conv, dim3(NTOT * 5), dim3(256), 0, stream, x, w1, b1, w2, b2, p2);
    hipLaunchKernelGGL(k_label, dim3(8), dim3(256), 0, stream, y, lbl);
    hipLaunchKernelGGL(k_enc, dim3(32 * KSPLIT), dim3(256), 0, stream, p2, encw, H);
    hipLaunchKernelGGL(k_stats, dim3(32), dim3(256), 0, stream, H, encb, lbl, t1w, t1b, cs, card);
    hipLaunchKernelGGL(k_head, dim3(1), dim3(256), 0, stream, cs, card,
                       te2w1, te2b1, te2w2, te2b2, t2w, t2b,
                       omw, omb, osw, osb, gaw, gab, gmw, gmb, gsw, gsb,
                       zew, zeb, zmw, zmb, zsw, zsb, out);
}

// Round 8
// 810.110 us; speedup vs baseline: 2.1743x; 2.1743x over previous
//
#include <hip/hip_runtime.h>
#include <math.h>

#define WAYS 32
#define NTOT 2048
#define XD 84
#define FLAT 3610
#define KSPLIT 16
#define KCHUNK 226  // ceil(3610/16)

__device__ __forceinline__ float softplus_f(float x) {
    return (x > 20.f) ? x : log1pf(expf(x));
}
__device__ __forceinline__ float kl_f(float mu, float sd) {
    return -logf(sd) + 0.5f * (sd * sd + mu * mu) - 0.5f;
}

// ---------------------------------------------------------------------------
// Fused conv1+relu+pool -> conv2+relu+pool.
// Grid: 2048 images x 5 bands of p2 rows (4,4,4,4,3).
// Spill-safe: oc split into 5-wide passes (acc[5][4]=20 live), c/ic loops
// pinned to unroll 1 (<=45 LDS weight loads in flight), compiler memory
// barrier per grid-stride iteration to stop invariant-load hoisting.
// ---------------------------------------------------------------------------
__global__ __launch_bounds__(256, 2) void k_conv(
        const float* __restrict__ x,
        const float* __restrict__ w1, const float* __restrict__ b1,
        const float* __restrict__ w2, const float* __restrict__ b2,
        float* __restrict__ p2) {
    __shared__ float xs[3 * 22 * 84];      // [c][row][col]  22176 B
    __shared__ float p1s[10 * 10 * 40];    // [ic][q][col]   16000 B
    __shared__ float w1s[270];             // native layout [oc][c][3][3]
    __shared__ float w2s[900];             // native layout [oc][ic][3][3]

    const int tid  = threadIdx.x;
    const int img  = blockIdx.x & 2047;
    const int band = blockIdx.x >> 11;       // 0..4
    const int r0   = band * 4;               // first p2 row
    const int nr   = (band < 4) ? 4 : 3;     // p2 rows in band
    const int nq   = 2 * nr + 2;             // p1 rows needed (10 or 8)
    const int xr0  = 16 * band;              // first x row (0,16,32,48,64)
    const int nxr  = 2 * nq + 2;             // x rows (22 or 18)

    // ---- stage x band (coalesced scalar copies) ----
    {
        const float* xg = x + (size_t)img * (3 * XD * XD);
        const int per_c = nxr * 84;          // 1848 or 1512
        #pragma unroll
        for (int c = 0; c < 3; c++) {
            const float* src = xg + c * (XD * XD) + xr0 * 84;
            float* dst = xs + c * (22 * 84);
            for (int i = tid; i < per_c; i += 256) dst[i] = src[i];
        }
    }
    // ---- stage weights (native layout, scalar copies) ----
    for (int i = tid; i < 270; i += 256) w1s[i] = w1[i];
    for (int i = tid; i < 900; i += 256) w2s[i] = w2[i];
    __syncthreads();

    // ---- conv1 + relu + pool -> p1s ----
    {
        const int n1 = nq * 40;              // 400 or 320
        #pragma unroll 1
        for (int it = tid; it < n1; it += 256) {
            asm volatile("" ::: "memory");   // no load hoisting across iters
            int q = it / 40;                 // local p1 row
            int p = it - q * 40;             // p1 col
            #pragma unroll 1
            for (int h = 0; h < 2; h++) {    // oc half: 0..4, 5..9
                float acc[5][4];
                #pragma unroll
                for (int o = 0; o < 5; o++)
                    #pragma unroll
                    for (int j = 0; j < 4; j++) acc[o][j] = 0.f;
                #pragma unroll 1
                for (int c = 0; c < 3; c++) {
                    float xp[4][4];
                    #pragma unroll
                    for (int rr = 0; rr < 4; rr++)
                        #pragma unroll
                        for (int cc = 0; cc < 4; cc++)
                            xp[rr][cc] = xs[c * (22 * 84) + (2 * q + rr) * 84 + (2 * p + cc)];
                    #pragma unroll
                    for (int ky = 0; ky < 3; ky++) {
                        #pragma unroll
                        for (int kx = 0; kx < 3; kx++) {
                            #pragma unroll
                            for (int o = 0; o < 5; o++) {
                                float w = w1s[((h * 5 + o) * 3 + c) * 9 + ky * 3 + kx];
                                acc[o][0] = fmaf(xp[ky][kx],         w, acc[o][0]);
                                acc[o][1] = fmaf(xp[ky][kx + 1],     w, acc[o][1]);
                                acc[o][2] = fmaf(xp[ky + 1][kx],     w, acc[o][2]);
                                acc[o][3] = fmaf(xp[ky + 1][kx + 1], w, acc[o][3]);
                            }
                        }
                    }
                }
                #pragma unroll
                for (int o = 0; o < 5; o++) {
                    int oc = h * 5 + o;
                    float m = fmaxf(fmaxf(acc[o][0], acc[o][1]), fmaxf(acc[o][2], acc[o][3]));
                    p1s[oc * 400 + q * 40 + p] = fmaxf(m + b1[oc], 0.f);
                }
            }
        }
    }
    __syncthreads();

    // ---- conv2 + relu + pool -> p2 (global) ----
    // 152 items: (pos 0..75) x (half 0..1); 5 output channels per item.
    {
        const int npos = nr * 19;            // 76 or 57
        if (tid < 152) {
            int half = (tid >= 76) ? 1 : 0;
            int pos  = tid - 76 * half;
            if (pos < npos) {
                int pr = pos / 19;           // local p2 row
                int pc = pos - pr * 19;
                float acc[5][4];
                #pragma unroll
                for (int o = 0; o < 5; o++)
                    #pragma unroll
                    for (int j = 0; j < 4; j++) acc[o][j] = 0.f;
                #pragma unroll 1
                for (int ic = 0; ic < 10; ic++) {
                    float xp[4][4];
                    #pragma unroll
                    for (int rr = 0; rr < 4; rr++)
                        #pragma unroll
                        for (int cc = 0; cc < 4; cc++)
                            xp[rr][cc] = p1s[ic * 400 + (2 * pr + rr) * 40 + (2 * pc + cc)];
                    #pragma unroll
                    for (int ky = 0; ky < 3; ky++) {
                        #pragma unroll
                        for (int kx = 0; kx < 3; kx++) {
                            #pragma unroll
                            for (int o = 0; o < 5; o++) {
                                float w = w2s[((half * 5 + o) * 10 + ic) * 9 + ky * 3 + kx];
                                acc[o][0] = fmaf(xp[ky][kx],         w, acc[o][0]);
                                acc[o][1] = fmaf(xp[ky][kx + 1],     w, acc[o][1]);
                                acc[o][2] = fmaf(xp[ky + 1][kx],     w, acc[o][2]);
                                acc[o][3] = fmaf(xp[ky + 1][kx + 1], w, acc[o][3]);
                            }
                        }
                    }
                }
                float* outp = p2 + (size_t)img * FLAT;
                #pragma unroll
                for (int o = 0; o < 5; o++) {
                    int oc = half * 5 + o;
                    float m = fmaxf(fmaxf(acc[o][0], acc[o][1]), fmaxf(acc[o][2], acc[o][3]));
                    outp[oc * 361 + (r0 + pr) * 19 + pc] = fmaxf(m + b2[oc], 0.f);
                }
            }
        }
    }
}

// ---------------------------------------------------------------------------
__global__ void k_label(const float* __restrict__ y, int* __restrict__ label) {
    int n = blockIdx.x * 256 + threadIdx.x;
    if (n >= NTOT) return;
    const float* yr = y + n * WAYS;
    float best = yr[0]; int bi = 0;
    for (int k = 1; k < WAYS; k++) {
        float v = yr[k];
        if (v > best) { best = v; bi = k; }
    }
    label[n] = bi;
}

// ---------------------------------------------------------------------------
// enc GEMM: H[2048,64] += p2[2048,3610] @ enc_w[3610,64]  (split-K, atomics)
// ---------------------------------------------------------------------------
__global__ __launch_bounds__(256, 2) void k_enc(
        const float* __restrict__ A, const float* __restrict__ W,
        float* __restrict__ H) {
    __shared__ float a_s[32 * 66];
    __shared__ float w_s[32 * 64];
    int mb = blockIdx.x >> 4;
    int ks = blockIdx.x & 15;
    int row0 = mb * 64;
    int kbeg = ks * KCHUNK;
    int kend = min(kbeg + KCHUNK, FLAT);
    int tid = threadIdx.x;
    int tr = tid & 15, tc = tid >> 4;
    float acc[4][4] = {};

    for (int k0 = kbeg; k0 < kend; k0 += 32) {
        {
            int kk = tid & 31;
            int r  = tid >> 5;
            int gk = k0 + kk;
            #pragma unroll
            for (int i = 0; i < 8; i++) {
                int rr = r + i * 8;
                float v = (gk < kend) ? A[(size_t)(row0 + rr) * FLAT + gk] : 0.f;
                a_s[kk * 66 + rr] = v;
            }
            int c  = tid & 63;
            int kw = tid >> 6;
            #pragma unroll
            for (int i = 0; i < 8; i++) {
                int kk2 = kw + i * 4;
                int gk2 = k0 + kk2;
                float v = (gk2 < kend) ? W[(size_t)gk2 * 64 + c] : 0.f;
                w_s[kk2 * 64 + c] = v;
            }
        }
        __syncthreads();
        #pragma unroll 8
        for (int k = 0; k < 32; k++) {
            float av[4], wv[4];
            #pragma unroll
            for (int i = 0; i < 4; i++) av[i] = a_s[k * 66 + tr * 4 + i];
            #pragma unroll
            for (int j = 0; j < 4; j++) wv[j] = w_s[k * 64 + tc * 4 + j];
            #pragma unroll
            for (int i = 0; i < 4; i++)
                #pragma unroll
                for (int j = 0; j < 4; j++)
                    acc[i][j] = fmaf(av[i], wv[j], acc[i][j]);
        }
        __syncthreads();
    }
    #pragma unroll
    for (int i = 0; i < 4; i++)
        #pragma unroll
        for (int j = 0; j < 4; j++)
            atomicAdd(&H[(size_t)(row0 + tr * 4 + i) * 64 + tc * 4 + j], acc[i][j]);
}

// ---------------------------------------------------------------------------
__global__ __launch_bounds__(256) void k_stats(
        const float* __restrict__ H, const float* __restrict__ encb,
        const int* __restrict__ label,
        const float* __restrict__ t1w, const float* __restrict__ t1b,
        float* __restrict__ cs, float* __restrict__ card) {
    __shared__ float rs[4][64], rs2[4][64];
    __shared__ int rc[4];
    int w = blockIdx.x;
    int tid = threadIdx.x;
    int c = tid & 63, g = tid >> 6;
    float s = 0.f, s2 = 0.f; int cnt = 0;
    for (int n = g; n < NTOT; n += 4) {
        if (label[n] == w) {
            float hv = H[n * 64 + c] + encb[c];
            s += hv; s2 += hv * hv; cnt++;
        }
    }
    rs[g][c] = s; rs2[g][c] = s2;
    if (c == 0) rc[g] = cnt;
    __syncthreads();
    if (g == 0) {
        float S  = rs[0][c] + rs[1][c] + rs[2][c] + rs[3][c];
        float S2 = rs2[0][c] + rs2[1][c] + rs2[2][c] + rs2[3][c];
        int CNT  = rc[0] + rc[1] + rc[2] + rc[3];
        float mean = S / 2048.f;
        float var  = (S2 - S * S / 2048.f) / 2047.f;
        float cd   = ((float)CNT - 1.f) / 63.f;
        #pragma unroll
        for (int j = 0; j < 4; j++)
            cs[w * 256 + c * 4 + j] =
                fmaxf(mean * t1w[j] + var * t1w[4 + j] + cd * t1w[8 + j] + t1b[j], 0.f);
        if (c == 0) card[w] = cd;
    }
}

// ---------------------------------------------------------------------------
__global__ __launch_bounds__(256) void k_head(
        const float* __restrict__ cs_g, const float* __restrict__ card,
        const float* __restrict__ te2w1, const float* __restrict__ te2b1,
        const float* __restrict__ te2w2, const float* __restrict__ te2b2,
        const float* __restrict__ t2w, const float* __restrict__ t2b,
        const float* __restrict__ omw, const float* __restrict__ omb,
        const float* __restrict__ osw, const float* __restrict__ osb,
        const float* __restrict__ gaw, const float* __restrict__ gab,
        const float* __restrict__ gmw, const float* __restrict__ gmb,
        const float* __restrict__ gsw, const float* __restrict__ gsb,
        const float* __restrict__ zew, const float* __restrict__ zeb,
        const float* __restrict__ zmw, const float* __restrict__ zmb,
        const float* __restrict__ zsw, const float* __restrict__ zsb,
        float* __restrict__ out) {
    __shared__ float cst[256 * 36];
    __shared__ float a1t[128 * 36];
    __shared__ float ts[32 * 32];
    __shared__ float tv[128];
    __shared__ float eg_s[64], ez_s[64];
    __shared__ float red[256];
    int tid = threadIdx.x;

    for (int i = tid; i < 32 * 256; i += 256) {
        int w = i >> 8, k = i & 255;
        cst[k * 36 + w] = cs_g[i];
    }
    __syncthreads();

    {
        int wg = tid >> 5, jg = tid & 31;
        int w0 = wg * 4, j0 = jg * 4;
        float acc[4][4] = {};
        for (int k = 0; k < 256; k++) {
            float cva[4], wva[4];
            #pragma unroll
            for (int i = 0; i < 4; i++) cva[i] = cst[k * 36 + w0 + i];
            #pragma unroll
            for (int j = 0; j < 4; j++) wva[j] = te2w1[k * 128 + j0 + j];
            #pragma unroll
            for (int i = 0; i < 4; i++)
                #pragma unroll
                for (int j = 0; j < 4; j++)
                    acc[i][j] = fmaf(cva[i], wva[j], acc[i][j]);
        }
        #pragma unroll
        for (int jj = 0; jj < 4; jj++) {
            float b = te2b1[j0 + jj];
            #pragma unroll
            for (int i = 0; i < 4; i++)
                a1t[(j0 + jj) * 36 + w0 + i] = fmaxf(acc[i][jj] + b, 0.f);
        }
    }
    __syncthreads();

    {
        int wg = tid >> 4, jg = tid & 15;
        int w0 = wg * 2, j0 = jg * 2;
        float acc[2][2] = {};
        for (int k = 0; k < 128; k++) {
            float a0 = a1t[k * 36 + w0];
            float a1 = a1t[k * 36 + w0 + 1];
            float b0 = te2w2[k * 32 + j0];
            float b1v = te2w2[k * 32 + j0 + 1];
            acc[0][0] = fmaf(a0, b0, acc[0][0]);
            acc[0][1] = fmaf(a0, b1v, acc[0][1]);
            acc[1][0] = fmaf(a1, b0, acc[1][0]);
            acc[1][1] = fmaf(a1, b1v, acc[1][1]);
        }
        #pragma unroll
        for (int i = 0; i < 2; i++)
            #pragma unroll
            for (int j = 0; j < 2; j++)
                ts[(w0 + i) * 32 + (j0 + j)] = acc[i][j] + te2b2[j0 + j];
    }
    __syncthreads();

    float muo = 0.f, sdo = 1.f;
    if (tid < 32) {
        float csum = 0.f;
        for (int w2 = 0; w2 < 32; w2++) csum += card[w2];
        float s = 0.f, s2 = 0.f;
        for (int w2 = 0; w2 < 32; w2++) { float v = ts[w2 * 32 + tid]; s += v; s2 += v * v; }
        float m  = s / 32.f;
        float vv = (s2 - s * s / 32.f) / 31.f;
        #pragma unroll
        for (int j = 0; j < 4; j++)
            tv[tid * 4 + j] = fmaxf(m * t2w[j] + vv * t2w[4 + j] + csum * t2w[8 + j] + t2b[j], 0.f);
    } else if (tid < 64) {
        int w = tid - 32;
        float am = 0.f, as = 0.f;
        for (int k = 0; k < 256; k++) {
            float cv = cst[k * 36 + w];
            am = fmaf(cv, omw[k], am);
            as = fmaf(cv, osw[k], as);
        }
        muo = fmaxf(am + omb[0], 0.f);
        sdo = softplus_f(fmaxf(as + osb[0], 0.f));
        out[w] = muo;
    }
    __syncthreads();

    if (tid >= 64 && tid < 128) {
        int j = tid - 64;
        float ag = gab[j], az = zeb[j];
        for (int k = 0; k < 128; k++) {
            float t = tv[k];
            ag = fmaf(t, gaw[k * 64 + j], ag);
            az = fmaf(t, zew[k * 64 + j], az);
        }
        eg_s[j] = fmaxf(ag, 0.f);
        ez_s[j] = fmaxf(az, 0.f);
    }
    __syncthreads();

    float r = 0.f;
    {
        int j = tid;
        float am = zmb[j], as = zsb[j];
        for (int k = 0; k < 64; k++) {
            float e = ez_s[k];
            am = fmaf(e, zmw[k * 256 + j], am);
            as = fmaf(e, zsw[k * 256 + j], as);
        }
        float mu = fmaxf(am, 0.f);
        float sd = softplus_f(fmaxf(as, 0.f));
        out[37 + j] = mu;
        r += kl_f(mu, sd);
    }
    if (tid < 5) {
        float am = gmb[tid], as = gsb[tid];
        for (int k = 0; k < 64; k++) {
            float e = eg_s[k];
            am = fmaf(e, gmw[k * 5 + tid], am);
            as = fmaf(e, gsw[k * 5 + tid], as);
        }
        float mu = fmaxf(am, 0.f);
        float sd = softplus_f(fmaxf(as, 0.f));
        out[32 + tid] = mu;
        r += kl_f(mu, sd);
    }
    if (tid >= 32 && tid < 64) r += kl_f(muo, sdo);
    red[tid] = r;
    __syncthreads();
    for (int s = 128; s > 0; s >>= 1) {
        if (tid < s) red[tid] += red[tid + s];
        __syncthreads();
    }
    if (tid == 0) out[293] = red[0];
}

// ---------------------------------------------------------------------------
extern "C" void kernel_launch(void* const* d_in, const int* in_sizes, int n_in,
                              void* d_out, int out_size, void* d_ws, size_t ws_size,
                              hipStream_t stream) {
    const float* x    = (const float*)d_in[0];
    const float* y    = (const float*)d_in[1];
    const float* w1   = (const float*)d_in[2];
    const float* b1   = (const float*)d_in[3];
    const float* w2   = (const float*)d_in[4];
    const float* b2   = (const float*)d_in[5];
    const float* encw = (const float*)d_in[6];
    const float* encb = (const float*)d_in[7];
    const float* t1w  = (const float*)d_in[8];
    const float* t1b  = (const float*)d_in[9];
    const float* te2w1 = (const float*)d_in[10];
    const float* te2b1 = (const float*)d_in[11];
    const float* te2w2 = (const float*)d_in[12];
    const float* te2b2 = (const float*)d_in[13];
    const float* t2w  = (const float*)d_in[14];
    const float* t2b  = (const float*)d_in[15];
    const float* omw  = (const float*)d_in[16];
    const float* omb  = (const float*)d_in[17];
    const float* osw  = (const float*)d_in[18];
    const float* osb  = (const float*)d_in[19];
    const float* gaw  = (const float*)d_in[20];
    const float* gab  = (const float*)d_in[21];
    const float* gmw  = (const float*)d_in[22];
    const float* gmb  = (const float*)d_in[23];
    const float* gsw  = (const float*)d_in[24];
    const float* gsb  = (const float*)d_in[25];
    const float* zew  = (const float*)d_in[26];
    const float* zeb  = (const float*)d_in[27];
    const float* zmw  = (const float*)d_in[28];
    const float* zmb  = (const float*)d_in[29];
    const float* zsw  = (const float*)d_in[30];
    const float* zsb  = (const float*)d_in[31];
    float* out = (float*)d_out;

    float* p2   = (float*)d_ws;                       // [2048][3610]
    float* H    = p2 + (size_t)NTOT * FLAT;           // [2048][64]
    int*   lbl  = (int*)(H + NTOT * 64);              // [2048]
    float* cs   = (float*)(lbl + NTOT);               // [32][256]
    float* card = cs + 32 * 256;                      // [32]

    hipMemsetAsync(H, 0, NTOT * 64 * sizeof(float), stream);
    hipLaunchKernelGGL(k_conv, dim3(NTOT * 5), dim3(256), 0, stream, x, w1, b1, w2, b2, p2);
    hipLaunchKernelGGL(k_label, dim3(8), dim3(256), 0, stream, y, lbl);
    hipLaunchKernelGGL(k_enc, dim3(32 * KSPLIT), dim3(256), 0, stream, p2, encw, H);
    hipLaunchKernelGGL(k_stats, dim3(32), dim3(256), 0, stream, H, encb, lbl, t1w, t1b, cs, card);
    hipLaunchKernelGGL(k_head, dim3(1), dim3(256), 0, stream, cs, card,
                       te2w1, te2b1, te2w2, te2b2, t2w, t2b,
                       omw, omb, osw, osb, gaw, gab, gmw, gmb, gsw, gsb,
                       zew, zeb, zmw, zmb, zsw, zsb, out);
}